// Round 2
// baseline (467.408 us; speedup 1.0000x reference)
//
#include <hip/hip_runtime.h>
#include <stdint.h>
#include <math.h>

// Problem geometry (fixed by the reference)
#define TT        256                       // T_STEPS
#define COLS      (16*8*1024*2)             // N*C*Do*Di = 262144
#define CS4       (COLS/4)                  // 65536
#define DMASK     (1024*2 - 1)              // Do*Di-1 (delay broadcast over N,C)

__device__ __forceinline__ uint32_t rotl32(uint32_t x, int n) {
    return (x << n) | (x >> (32 - n));
}

// JAX threefry2x32-20 with jax_threefry_partitionable=True (default in
// modern JAX): per-element counter = (hi32(i), lo32(i)) = (0, i) here,
// output bits = x0_final ^ x1_final. Key = jax.random.key(42) = (0, 42).
// (Core verified vs Random123 KAT: key=(0,0), ctr=(0,0) -> 6b200159/99ba4efe.)
__device__ __forceinline__ uint32_t jax_bits_partitionable(uint32_t j) {
    uint32_t x0 = 0u, x1 = j;
    const uint32_t ks0 = 0u;
    const uint32_t ks1 = 42u;
    const uint32_t ks2 = 0x1BD11BDAu ^ 0u ^ 42u;
    x0 += ks0; x1 += ks1;
#define RND(r) { x0 += x1; x1 = rotl32(x1, r); x1 ^= x0; }
    RND(13) RND(15) RND(26) RND(6)
    x0 += ks1; x1 += ks2 + 1u;
    RND(17) RND(29) RND(16) RND(24)
    x0 += ks2; x1 += ks0 + 2u;
    RND(13) RND(15) RND(26) RND(6)
    x0 += ks0; x1 += ks1 + 3u;
    RND(17) RND(29) RND(16) RND(24)
    x0 += ks1; x1 += ks2 + 4u;
    RND(13) RND(15) RND(26) RND(6)
    x0 += ks2; x1 += ks0 + 5u;
#undef RND
    return x0 ^ x1;
}

__device__ __forceinline__ float sigmoidf_(float x) {
    return 1.0f / (1.0f + expf(-x));
}

// Kernel A: per column j in [0,COLS): argmax_t sigmoid(in[t,j]) (first max,
// strict >, matching jnp.argmax), then JAX-bit-exact bernoulli rounding of
// delay, clamp by (T-1-argmax), store int32 delay to darr.
extern "C" __global__ __launch_bounds__(256)
void td_prep(const float* __restrict__ in, const float* __restrict__ delay,
             int* __restrict__ darr) {
    const int j4 = blockIdx.x * 256 + threadIdx.x;     // 0 .. CS4-1
    const float4* in4 = (const float4*)in;

    float b0 = -1.0f, b1 = -1.0f, b2 = -1.0f, b3 = -1.0f;  // sigmoid in (0,1)
    int   i0 = 0, i1 = 0, i2 = 0, i3 = 0;
#pragma unroll 8
    for (int t = 0; t < TT; ++t) {
        float4 v = in4[(size_t)t * CS4 + j4];
        float s0 = sigmoidf_(v.x);
        float s1 = sigmoidf_(v.y);
        float s2 = sigmoidf_(v.z);
        float s3 = sigmoidf_(v.w);
        if (s0 > b0) { b0 = s0; i0 = t; }
        if (s1 > b1) { b1 = s1; i1 = t; }
        if (s2 > b2) { b2 = s2; i2 = t; }
        if (s3 > b3) { b3 = s3; i3 = t; }
    }

    const int j = j4 * 4;
    int am[4] = { i0, i1, i2, i3 };
#pragma unroll
    for (int k = 0; k < 4; ++k) {
        const int jj = j + k;
        float dl = delay[jj & DMASK];          // broadcast over (N,C)
        float df = floorf(dl);
        float fr = dl - df;                    // exact in fp32 (matches JAX)
        uint32_t bits = jax_bits_partitionable((uint32_t)jj);
        float u = __uint_as_float((bits >> 9) | 0x3f800000u) - 1.0f;  // [0,1)
        float dr = (u < fr) ? df + 1.0f : df;  // bernoulli round
        float cl = (float)(TT - 1 - am[k]);    // spike-no-wrap clamp
        dr = fminf(dr, cl);
        darr[jj] = (int)dr;
    }
}

// Kernel B: out[t, j] = sigmoid(in[(t - d_j) mod T, j]); float4 stores,
// scalar gather loads (d differs per column). Each input element is read
// exactly once; gather window (~31 planes = 31 MiB) is L3-resident.
extern "C" __global__ __launch_bounds__(256)
void td_apply(const float* __restrict__ in, const int* __restrict__ darr,
              float* __restrict__ out) {
    const int t  = blockIdx.y;
    const int j4 = blockIdx.x * 256 + threadIdx.x;
    const int j  = j4 * 4;
    int4 d = ((const int4*)darr)[j4];

    int s0 = t - d.x; s0 += (s0 >> 31) & TT;
    int s1 = t - d.y; s1 += (s1 >> 31) & TT;
    int s2 = t - d.z; s2 += (s2 >> 31) & TT;
    int s3 = t - d.w; s3 += (s3 >> 31) & TT;

    float4 o;
    o.x = sigmoidf_(in[(size_t)s0 * COLS + j + 0]);
    o.y = sigmoidf_(in[(size_t)s1 * COLS + j + 1]);
    o.z = sigmoidf_(in[(size_t)s2 * COLS + j + 2]);
    o.w = sigmoidf_(in[(size_t)s3 * COLS + j + 3]);

    ((float4*)out)[(size_t)t * CS4 + j4] = o;
}

extern "C" void kernel_launch(void* const* d_in, const int* in_sizes, int n_in,
                              void* d_out, int out_size, void* d_ws, size_t ws_size,
                              hipStream_t stream) {
    const float* in    = (const float*)d_in[0];   // (T,N,C,Do,Di) f32
    const float* delay = (const float*)d_in[1];   // (Do,Di) f32
    float* out = (float*)d_out;
    int*   dar = (int*)d_ws;                      // COLS int32 = 1 MiB scratch

    hipLaunchKernelGGL(td_prep,  dim3(CS4 / 256),     dim3(256), 0, stream,
                       in, delay, dar);
    hipLaunchKernelGGL(td_apply, dim3(CS4 / 256, TT), dim3(256), 0, stream,
                       in, dar, out);
}

// Round 3
// 121.789 us; speedup vs baseline: 3.8379x; 3.8379x over previous
//
#include <hip/hip_runtime.h>
#include <stdint.h>
#include <math.h>

// Problem geometry (fixed by the reference)
#define TT        256                       // T_STEPS
#define COLS      (16*8*1024*2)             // N*C*Do*Di = 262144
#define CS4       (COLS/4)                  // 65536
#define DMASK     (1024*2 - 1)              // Do*Di-1 (delay broadcast over N,C)
#define W         64                        // columns per block

__device__ __forceinline__ uint32_t rotl32(uint32_t x, int n) {
    return (x << n) | (x >> (32 - n));
}

// JAX threefry2x32-20, jax_threefry_partitionable=True (modern default):
// per-element counter (0, j), output = x0 ^ x1. Key = PRNGKey(42) = (0,42).
// Verified passing in round 2 — DO NOT TOUCH.
__device__ __forceinline__ uint32_t jax_bits_partitionable(uint32_t j) {
    uint32_t x0 = 0u, x1 = j;
    const uint32_t ks0 = 0u;
    const uint32_t ks1 = 42u;
    const uint32_t ks2 = 0x1BD11BDAu ^ 0u ^ 42u;
    x0 += ks0; x1 += ks1;
#define RND(r) { x0 += x1; x1 = rotl32(x1, r); x1 ^= x0; }
    RND(13) RND(15) RND(26) RND(6)
    x0 += ks1; x1 += ks2 + 1u;
    RND(17) RND(29) RND(16) RND(24)
    x0 += ks2; x1 += ks0 + 2u;
    RND(13) RND(15) RND(26) RND(6)
    x0 += ks0; x1 += ks1 + 3u;
    RND(17) RND(29) RND(16) RND(24)
    x0 += ks1; x1 += ks2 + 4u;
    RND(13) RND(15) RND(26) RND(6)
    x0 += ks2; x1 += ks0 + 5u;
#undef RND
    return x0 ^ x1;
}

__device__ __forceinline__ float sigmoidf_(float x) {
    return 1.0f / (1.0f + expf(-x));   // same formula as the passing round
}

// Fused kernel: block owns columns [c0, c0+W) for all T.
//  phase 1 : coalesced float4 load of the 256xW tile, sigmoid once, -> LDS
//  phase 1b: per-column argmax over sigma (first-max, strict >), 4-seg reduce,
//            threefry bernoulli round + spike clamp -> d[c]
//  phase 2 : out[r, c] = tile[(r - d_c) & 255][c]  (conflict-free LDS read,
//            256B/wave coalesced global store)
extern "C" __global__ __launch_bounds__(256)
void td_fused(const float* __restrict__ in, const float* __restrict__ delay,
              float* __restrict__ out) {
    __shared__ float tile[TT * W];          // 64 KiB sigma tile
    __shared__ float redv[4][W];
    __shared__ int   redi[4][W];
    __shared__ int   dint[W];

    const int c0  = blockIdx.x * W;
    const int tid = threadIdx.x;

    // ---- phase 1: load + sigmoid -> LDS ----
    const float4* in4 = (const float4*)in;
    const int f  = tid & 15;                // float4 slot within a t-row
    const int r0 = tid >> 4;                // 0..15
#pragma unroll 4
    for (int k = 0; k < 16; ++k) {
        const int t = r0 + (k << 4);
        float4 v = in4[(size_t)t * CS4 + (c0 >> 2) + f];
        float4 s;
        s.x = sigmoidf_(v.x);
        s.y = sigmoidf_(v.y);
        s.z = sigmoidf_(v.z);
        s.w = sigmoidf_(v.w);
        *(float4*)&tile[t * W + (f << 2)] = s;
    }
    __syncthreads();

    // ---- phase 1b: segmented argmax along T (strict >, first index) ----
    const int c   = tid & 63;
    const int seg = tid >> 6;               // wave id, 0..3
    {
        const int sbase = seg << 6;         // 64 rows per segment
        float bm = -1.0f;                   // sigma in (0,1)
        int   bi = sbase;
        for (int s = 0; s < 64; ++s) {
            float v = tile[(sbase + s) * W + c];
            if (v > bm) { bm = v; bi = sbase + s; }
        }
        redv[seg][c] = bm;
        redi[seg][c] = bi;
    }
    __syncthreads();

    if (tid < W) {
        float bm = redv[0][tid]; int bi = redi[0][tid];
#pragma unroll
        for (int s2 = 1; s2 < 4; ++s2) {
            float v = redv[s2][tid];
            if (v > bm) { bm = v; bi = redi[s2][tid]; }  // earlier seg wins ties
        }
        const int jj = c0 + tid;
        float dl = delay[jj & DMASK];       // broadcast over (N,C)
        float df = floorf(dl);
        float fr = dl - df;                 // exact in fp32 (matches JAX)
        uint32_t bits = jax_bits_partitionable((uint32_t)jj);
        float u = __uint_as_float((bits >> 9) | 0x3f800000u) - 1.0f;  // [0,1)
        float dr = (u < fr) ? df + 1.0f : df;
        dr = fminf(dr, (float)(TT - 1 - bi));   // spike-no-wrap clamp
        dint[tid] = (int)dr;
    }
    __syncthreads();

    // ---- phase 2: rotate + write out ----
    const int d = dint[c];
    const int w = tid >> 6;                 // 0..3
#pragma unroll 4
    for (int k = 0; k < 64; ++k) {
        const int r = (k << 2) + w;
        const int s = (r - d) & (TT - 1);
        out[(size_t)r * COLS + c0 + c] = tile[s * W + c];
    }
}

extern "C" void kernel_launch(void* const* d_in, const int* in_sizes, int n_in,
                              void* d_out, int out_size, void* d_ws, size_t ws_size,
                              hipStream_t stream) {
    const float* in    = (const float*)d_in[0];   // (T,N,C,Do,Di) f32
    const float* delay = (const float*)d_in[1];   // (Do,Di) f32
    float* out = (float*)d_out;

    hipLaunchKernelGGL(td_fused, dim3(COLS / W), dim3(256), 0, stream,
                       in, delay, out);
}